// Round 8
// baseline (208.616 us; speedup 1.0000x reference)
//
#include <hip/hip_runtime.h>

// RPN target generation for MI355X — 2-node pipeline (main + finalize).
// Outputs (float32, concat): [0,A) rpn_match; [A,5A) rpn_bbox (A x 4); [5A] num_positives.
//
// Lessons baked in (calibrated across R2-R7):
//  * memory-side same-address atomics ~100ns/op -> NO O(grid) same-address atomics.
//  * DS queue is in-order -> no per-iter LDS atomics/shuffles in the hot loop;
//    per-lane VGPR bitmask + sparse post-loop drain instead.
//  * ~15us/graph-node overhead -> fold merge into main (best/bg thread-local),
//    kill the memset by making the cross-block gt-reduction PLAIN STORES into
//    per-block rows (every slot written -> 0xAA ws poison harmless).
//
// ws layout: [0, nb*256*8)  gkeyC u64 per-(block, gt) argmax keys (plain stores)
//            [.., +nb*4)    pcount i32 per-block positive counts (plain stores)

#define GMAX 256

// Faithful to the reference, including the intentional size "bug":
// gt_size = y2 + y1 (not y2 - y1); centre = 0.5 * (y1 + y2).
__device__ __forceinline__ float4 compute_deltas(float4 ab, float4 gb,
                                                 const float* __restrict__ sd) {
    float sy_g = gb.z + gb.x;   // box = (y1, x1, y2, x2) in (x,y,z,w)
    float sx_g = gb.w + gb.y;
    float sy_a = ab.z + ab.x;
    float sx_a = ab.w + ab.y;
    float4 d;
    d.x = (0.5f * (sy_g - sy_a) / sy_a) / sd[0];
    d.y = (0.5f * (sx_g - sx_a) / sx_a) / sd[1];
    d.z = logf(sy_g / sy_a) / sd[2];
    d.w = logf(sx_g / sx_a) / sd[3];
    return d;
}

__device__ __forceinline__ float iou_of(float4 ab, float a_area, float4 gb) {
    float y1 = fmaxf(ab.x, gb.x);
    float x1 = fmaxf(ab.y, gb.y);
    float y2 = fminf(ab.z, gb.z);
    float x2 = fminf(ab.w, gb.w);
    float inter = fmaxf(y2 - y1, 0.f) * fmaxf(x2 - x1, 0.f);
    float garea = (gb.z - gb.x) * (gb.w - gb.y);
    float uni = (a_area + garea) - inter;
    return inter * __builtin_amdgcn_rcpf(uni);   // exact 0 if inter==0
}

// ---------- kernel 1: full sweep, outputs inline, per-block gt rows ----------
__global__ __launch_bounds__(256) void rpn_main(
    const float4* __restrict__ anchors,       // [A]
    const int* __restrict__ valid,            // [A] jnp bool as int32
    const int* __restrict__ cls,              // [G]
    const float4* __restrict__ gt,            // [G]
    const float* __restrict__ stdev,          // [4]
    float* __restrict__ out,                  // [5A+1]
    unsigned long long* __restrict__ gkeyC,   // [nb*GMAX] plain stores
    int* __restrict__ pcount,                 // [nb] plain stores
    int A, int G)
{
    __shared__ float4 s_gt[GMAX];
    __shared__ float s_crowdf[GMAX];
    __shared__ unsigned long long s_key[GMAX];
    __shared__ int s_anycrowd;
    __shared__ int s_cnt;

    const int tid = threadIdx.x;
    if (tid == 0) { s_anycrowd = 0; s_cnt = 0; }
    s_key[tid] = 0ULL;                        // all 256 slots (row store covers GMAX)
    if (tid < G) {
        s_gt[tid] = gt[tid];
        int c = cls[tid];
        s_crowdf[tid] = (c < 0) ? 1.0f : 0.0f;
        if (c < 0) s_anycrowd = 1;            // benign race, same value
    }
    __syncthreads();
    const int any_crowd = s_anycrowd;

    const int ai = blockIdx.x * 256 + tid;
    const bool in_range = (ai < A);
    float4 ab = in_range ? anchors[ai] : make_float4(0.f, 0.f, 1.f, 1.f);
    const bool v = in_range && (valid[ai] != 0);
    const float a_area = (ab.z - ab.x) * (ab.w - ab.y);

    float best;
    int bg = 0;
    float crowd_max = 0.0f;
    unsigned long long m0 = 0ULL, m1 = 0ULL, m2 = 0ULL, m3 = 0ULL;

    if (!any_crowd && G == GMAX) {
        // ---- fast path ----
        best = -1.0f;
        #pragma unroll
        for (int w = 0; w < 4; ++w) {
            unsigned long long m = 0ULL;
            #pragma unroll 8
            for (int j = 0; j < 64; ++j) {
                int g = (w << 6) + j;
                float4 gb = s_gt[g];           // ds_read_b128, broadcast
                float y1 = fmaxf(ab.x, gb.x);
                float x1 = fmaxf(ab.y, gb.y);
                float y2 = fminf(ab.z, gb.z);
                float x2 = fminf(ab.w, gb.w);
                float inter = fmaxf(y2 - y1, 0.f) * fmaxf(x2 - x1, 0.f);
                float garea = (gb.z - gb.x) * (gb.w - gb.y);
                float iou = inter * __builtin_amdgcn_rcpf((a_area + garea) - inter);
                if (iou > best) { best = iou; bg = g; }        // first-index tie-break
                if (iou > 0.0f) m |= (1ULL << j);
            }
            if (w == 0) m0 = m; else if (w == 1) m1 = m; else if (w == 2) m2 = m; else m3 = m;
        }
    } else {
        // ---- general path: crowd / odd G (correctness-only) ----
        best = -2.0f;
        for (int g = 0; g < G; ++g) {
            float4 gb = s_gt[g];
            float iou = iou_of(ab, a_area, gb);
            float cf = s_crowdf[g];
            float eff = (cf != 0.0f) ? -1.0f : iou;
            if (eff > best) { best = eff; bg = g; }
            crowd_max = fmaxf(crowd_max, iou * cf);
            if (cf == 0.0f && iou > 0.0f) {
                int w = g >> 6, j = g & 63;
                if (w == 0) m0 |= (1ULL << j); else if (w == 1) m1 |= (1ULL << j);
                else if (w == 2) m2 |= (1ULL << j); else m3 |= (1ULL << j);
            }
        }
    }

    // ---- outputs (merge fused in: everything is thread-local) ----
    bool no_crowd = any_crowd ? (crowd_max < 0.001f) : true;
    bool pos = (best >= 0.7f);
    bool neg = (best < 0.3f) && no_crowd && !pos;
    bool posv = pos && v;

    if (in_range) {
        out[ai] = v ? (pos ? 1.0f : (neg ? -1.0f : 0.0f)) : 0.0f;
        float4 d = make_float4(0.f, 0.f, 0.f, 0.f);
        if (posv) d = compute_deltas(ab, s_gt[bg], stdev);
        ((float4*)(out + A))[ai] = d;
    }

    // ---- sparse drain (~5 bits/lane): rare LDS atomicMax into s_key ----
    if (v) {
        const unsigned lokey = ~(unsigned)ai;   // smaller ai -> larger lokey
        #pragma unroll
        for (int w = 0; w < 4; ++w) {
            unsigned long long m = (w == 0) ? m0 : (w == 1) ? m1 : (w == 2) ? m2 : m3;
            while (m != 0ULL) {
                int j = __builtin_ctzll(m); m &= (m - 1ULL);
                int g = (w << 6) + j;
                float iou = iou_of(ab, a_area, s_gt[g]);
                atomicMax(&s_key[g],
                    (((unsigned long long)(__float_as_uint(iou) + 1u)) << 32) | lokey);
            }
        }
    }

    unsigned long long pv = __ballot((int)posv);
    if ((tid & 63) == 0) atomicAdd(&s_cnt, (int)__popcll(pv));   // LDS only
    __syncthreads();

    // plain coalesced stores: every slot written -> no init, no atomics
    gkeyC[(size_t)blockIdx.x * GMAX + tid] = s_key[tid];
    if (tid == 0) pcount[blockIdx.x] = s_cnt;
}

// ---------- kernel 2: single-block finalize ----------
__global__ __launch_bounds__(1024) void rpn_finalize(
    const float4* __restrict__ anchors,
    const int* __restrict__ valid,
    const int* __restrict__ cls,
    const float4* __restrict__ gt,
    const float* __restrict__ stdev,
    float* __restrict__ out,
    const unsigned long long* __restrict__ gkeyC,
    const int* __restrict__ pcount,
    int nb, int A, int G)
{
    __shared__ float4 s_gt[GMAX];
    __shared__ float s_crowdf[GMAX];
    __shared__ unsigned long long s_part[4][GMAX];
    __shared__ int s_tot[1024];
    __shared__ int s_cnt;

    const int tid = threadIdx.x;
    if (tid == 0) s_cnt = 0;
    if (tid < G) {
        s_gt[tid] = gt[tid];
        s_crowdf[tid] = (cls[tid] < 0) ? 1.0f : 0.0f;
    }

    // sum per-block positive counts
    int acc = 0;
    for (int i = tid; i < nb; i += 1024) acc += pcount[i];
    s_tot[tid] = acc;

    // 4-way split column-max over the nb x 256 key matrix (coalesced rows)
    {
        const int g = tid & (GMAX - 1);
        const int part = tid >> 8;             // 0..3
        unsigned long long key = 0ULL;
        for (int c = part; c < nb; c += 4) {
            unsigned long long k = gkeyC[(size_t)c * GMAX + g];
            if (k > key) key = k;
        }
        s_part[part][g] = key;
    }
    __syncthreads();
    for (int s = 512; s > 0; s >>= 1) {
        if (tid < s) s_tot[tid] += s_tot[tid + s];
        __syncthreads();
    }

    if (tid < G && s_crowdf[tid] == 0.0f) {    // scatter value is False for crowd gts
        unsigned long long key = s_part[0][tid];
        if (s_part[1][tid] > key) key = s_part[1][tid];
        if (s_part[2][tid] > key) key = s_part[2][tid];
        if (s_part[3][tid] > key) key = s_part[3][tid];
        int w;
        if (key != 0ULL) {
            w = (int)(~(unsigned)(key & 0xFFFFFFFFull));
        } else {
            // no valid anchor overlapped this gt: first valid anchor, else 0
            w = 0;
            for (int i = 0; i < A; ++i) { if (valid[i] != 0) { w = i; break; } }
        }
        if (valid[w] != 0) {
            float old = atomicExch(out + w, 1.0f);   // <=256 ops, mostly distinct
            if (old != 1.0f) {
                float4 ab2 = anchors[w];
                float a2 = (ab2.z - ab2.x) * (ab2.w - ab2.y);
                float b2 = -2.0f; int g2 = 0;
                for (int g = 0; g < G; ++g) {
                    float iou = iou_of(ab2, a2, s_gt[g]);
                    float eff = (s_crowdf[g] != 0.0f) ? -1.0f : iou;
                    if (eff > b2) { b2 = eff; g2 = g; }
                }
                ((float4*)(out + A))[w] = compute_deltas(ab2, s_gt[g2], stdev);
                atomicAdd(&s_cnt, 1);
            }
        }
    }
    __syncthreads();
    if (tid == 0) out[(size_t)5 * A] = (float)(s_tot[0] + s_cnt);
}

// ---------------- fallback: monolithic kernel (used only if ws too small) ------
__global__ __launch_bounds__(256) void rpn_fused(
    const float4* __restrict__ anchors, const int* __restrict__ valid,
    const int* __restrict__ cls, const float4* __restrict__ gt,
    const float* __restrict__ stdev, float* __restrict__ out,
    unsigned long long* __restrict__ gkey, unsigned* __restrict__ done,
    int* __restrict__ cnt, int A, int G)
{
    __shared__ float4 s_gt[GMAX];
    __shared__ float s_crowdf[GMAX];
    __shared__ unsigned long long s_key[GMAX];
    __shared__ int s_anycrowd; __shared__ int s_cnt; __shared__ int s_islast;

    const int tid = threadIdx.x;
    if (tid == 0) { s_anycrowd = 0; s_cnt = 0; }
    if (tid < G) {
        s_gt[tid] = gt[tid];
        int c = cls[tid];
        s_crowdf[tid] = (c < 0) ? 1.0f : 0.0f;
        if (c < 0) s_anycrowd = 1;
        s_key[tid] = 0ULL;
    }
    __syncthreads();
    const int any_crowd = s_anycrowd;
    const int ai = blockIdx.x * 256 + tid;
    const bool in_range = (ai < A);
    float4 ab = in_range ? anchors[ai] : make_float4(0.f, 0.f, 1.f, 1.f);
    const bool v = in_range && (valid[ai] != 0);
    const float a_area = (ab.z - ab.x) * (ab.w - ab.y);
    const unsigned lokey = ~(unsigned)ai;

    float best = any_crowd ? -2.0f : -1.0f;
    int bg = 0; float crowd_max = 0.0f;
    unsigned long long ovmask[4];
    #pragma unroll
    for (int w = 0; w < 4; ++w) {
        unsigned long long m = 0ULL;
        #pragma unroll 4
        for (int j = 0; j < 64; ++j) {
            int g = (w << 6) + j;
            if (g >= G) break;
            float iou = iou_of(ab, a_area, s_gt[g]);
            float cf = s_crowdf[g];
            float eff = (any_crowd && cf != 0.0f) ? -1.0f : iou;
            if (eff > best) { best = eff; bg = g; }
            if (any_crowd) crowd_max = fmaxf(crowd_max, iou * cf);
            if (v && (cf == 0.0f) && iou > 0.0f) m |= (1ULL << j);
        }
        ovmask[w] = m;
    }
    #pragma unroll
    for (int w = 0; w < 4; ++w) {
        unsigned long long m = ovmask[w];
        while (m != 0ULL) {
            int j = __builtin_ctzll(m); m &= (m - 1ULL);
            int g = (w << 6) + j;
            float iou = iou_of(ab, a_area, s_gt[g]);
            atomicMax(&s_key[g],
                (((unsigned long long)(__float_as_uint(iou) + 1u)) << 32) | lokey);
        }
    }
    bool no_crowd = any_crowd ? (crowd_max < 0.001f) : true;
    bool pos = (best >= 0.7f);
    bool neg = (best < 0.3f) && no_crowd && !pos;
    unsigned long long pv = __ballot((int)(in_range && pos && v));
    if ((tid & 63) == 0) atomicAdd(&s_cnt, (int)__popcll(pv));
    if (in_range) {
        out[ai] = v ? (pos ? 1.0f : (neg ? -1.0f : 0.0f)) : 0.0f;
        float4 d = make_float4(0.f, 0.f, 0.f, 0.f);
        if (pos && v) d = compute_deltas(ab, s_gt[bg], stdev);
        ((float4*)(out + A))[ai] = d;
    }
    __syncthreads();
    if (tid < G && s_key[tid] != 0ULL) atomicMax(&gkey[tid], s_key[tid]);
    if (tid == 0 && s_cnt > 0) atomicAdd(cnt, s_cnt);
    __threadfence();
    if (tid == 0) {
        unsigned prev = atomicAdd(done, 1u);
        s_islast = (prev == gridDim.x - 1);
        s_cnt = 0;
    }
    __syncthreads();
    if (!s_islast) return;
    __threadfence();
    if (tid < G && s_crowdf[tid] == 0.0f) {
        unsigned long long key = gkey[tid];
        int w;
        if (key != 0ULL) w = (int)(~(unsigned)(key & 0xFFFFFFFFull));
        else { w = 0; for (int i = 0; i < A; ++i) { if (valid[i] != 0) { w = i; break; } } }
        if (valid[w] != 0) {
            float old = atomicExch(out + w, 1.0f);
            if (old != 1.0f) {
                float4 ab2 = anchors[w];
                float a2 = (ab2.z - ab2.x) * (ab2.w - ab2.y);
                float b2 = -2.0f; int g2 = 0;
                for (int g = 0; g < G; ++g) {
                    float iou = iou_of(ab2, a2, s_gt[g]);
                    float eff = (s_crowdf[g] != 0.0f) ? -1.0f : iou;
                    if (eff > b2) { b2 = eff; g2 = g; }
                }
                ((float4*)(out + A))[w] = compute_deltas(ab2, s_gt[g2], stdev);
                atomicAdd(&s_cnt, 1);
            }
        }
    }
    __syncthreads();
    if (tid == 0) out[(size_t)5 * A] = (float)(*cnt + s_cnt);
}

extern "C" void kernel_launch(void* const* d_in, const int* in_sizes, int n_in,
                              void* d_out, int out_size, void* d_ws, size_t ws_size,
                              hipStream_t stream) {
    const float4* anchors = (const float4*)d_in[0];
    const int* valid      = (const int*)d_in[1];   // jnp bool -> int32 per element
    const int* cls        = (const int*)d_in[2];
    const float4* gt      = (const float4*)d_in[3];
    const float* stdev    = (const float*)d_in[4];
    float* out            = (float*)d_out;

    const int A = in_sizes[0] / 4;
    const int G = in_sizes[2];                     // 256
    const int nb = (A + 255) / 256;                // 1023

    const size_t gkey_bytes = (size_t)nb * GMAX * 8;   // ~2.1 MB
    const size_t pcnt_bytes = (size_t)nb * 4;
    const size_t needed = gkey_bytes + pcnt_bytes;

    if (ws_size >= needed && G <= GMAX) {
        unsigned long long* gkeyC = (unsigned long long*)d_ws;
        int* pcount = (int*)((char*)d_ws + gkey_bytes);

        rpn_main<<<nb, 256, 0, stream>>>(anchors, valid, cls, gt, stdev, out,
                                         gkeyC, pcount, A, G);
        rpn_finalize<<<1, 1024, 0, stream>>>(anchors, valid, cls, gt, stdev, out,
                                             gkeyC, pcount, nb, A, G);
    } else {
        unsigned long long* gkey = (unsigned long long*)d_ws;
        unsigned* done = (unsigned*)((char*)d_ws + 2048);
        int* cnt       = (int*)((char*)d_ws + 2052);
        hipMemsetAsync(d_ws, 0, 2056, stream);
        rpn_fused<<<nb, 256, 0, stream>>>(anchors, valid, cls, gt, stdev, out,
                                          gkey, done, cnt, A, G);
    }
}